// Round 4
// baseline (1033.880 us; speedup 1.0000x reference)
//
#include <hip/hip_runtime.h>

// 2-layer hetero SAGEConv, atomic-free aggregation:
//   radix partition of edges by dst-bucket (LDS histograms, deterministic slots)
//   -> per-bucket LDS-accumulator mean -> dense tile GEMMs.
//  - (msum/cnt)@W == (msum@W)/cnt
//  - Wl2 fused in-tile into the var-layer GEMM (h_var never stored; layer-2
//    aggregation runs on 64-dim hv2 reusing the v2c partition).
//  - to_dense_batch is an identity reshape (batch = arange(NC)//K).

#define CHUNK 4096      // edges per partition block
#define EPT 16          // edges per thread (CHUNK/256)
#define MAXBINS 1024

// ---- partition phase 1: counts[bin][block], no global atomics ----
__global__ __launch_bounds__(256) void part_count2_kernel(
    const int* __restrict__ dstC, const int* __restrict__ dstV, int E, int nblocks,
    int nbinsC, int nbinsV, int* __restrict__ countsC, int* __restrict__ countsV) {
    const int* dst; int shift, nbins; int* counts; int b;
    if (blockIdx.x < (unsigned)nblocks) { dst = dstC; shift = 6; nbins = nbinsC; counts = countsC; b = blockIdx.x; }
    else { dst = dstV; shift = 7; nbins = nbinsV; counts = countsV; b = blockIdx.x - nblocks; }
    __shared__ int hist[MAXBINS];
    int t = threadIdx.x;
    for (int j = t; j < nbins; j += 256) hist[j] = 0;
    __syncthreads();
    int base = b * CHUNK;
#pragma unroll
    for (int j = 0; j < EPT; ++j) {
        int e = base + j * 256 + t;
        if (e < E) atomicAdd(&hist[dst[e] >> shift], 1);
    }
    __syncthreads();
    for (int j = t; j < nbins; j += 256) counts[(size_t)j * nblocks + b] = hist[j];
}

// ---- phase 2a: per-bin exclusive prefix over blocks; binTot ----
__global__ __launch_bounds__(256) void part_rowscan2_kernel(
    int* __restrict__ countsC, int nbinsC, int* __restrict__ binTotC,
    int* __restrict__ countsV, int* __restrict__ binTotV, int nblocks) {
    int* counts; int* binTot; int bin;
    if (blockIdx.x < (unsigned)nbinsC) { counts = countsC; binTot = binTotC; bin = blockIdx.x; }
    else { counts = countsV; binTot = binTotV; bin = blockIdx.x - nbinsC; }
    __shared__ int s[256];
    int t = threadIdx.x;
    int v = (t < nblocks) ? counts[(size_t)bin * nblocks + t] : 0;
    s[t] = v; __syncthreads();
    for (int o = 1; o < 256; o <<= 1) {
        int add = (t >= o) ? s[t - o] : 0; __syncthreads();
        s[t] += add; __syncthreads();
    }
    if (t < nblocks) counts[(size_t)bin * nblocks + t] = s[t] - v;
    if (t == nblocks - 1) binTot[bin] = s[t];
}

// ---- phase 2b: exclusive prefix over bins ----
__global__ __launch_bounds__(256) void part_binscan2_kernel(
    const int* __restrict__ binTotC, int nbinsC, int* __restrict__ binBaseC,
    const int* __restrict__ binTotV, int nbinsV, int* __restrict__ binBaseV) {
    const int* binTot; int nbins; int* binBase;
    if (blockIdx.x == 0) { binTot = binTotC; nbins = nbinsC; binBase = binBaseC; }
    else { binTot = binTotV; nbins = nbinsV; binBase = binBaseV; }
    __shared__ int s[256];
    __shared__ int carry;
    int t = threadIdx.x;
    if (t == 0) carry = 0;
    __syncthreads();
    for (int c0 = 0; c0 < nbins; c0 += 256) {
        int v = (c0 + t < nbins) ? binTot[c0 + t] : 0;
        s[t] = v; __syncthreads();
        for (int o = 1; o < 256; o <<= 1) {
            int add = (t >= o) ? s[t - o] : 0; __syncthreads();
            s[t] += add; __syncthreads();
        }
        if (c0 + t < nbins) binBase[c0 + t] = carry + s[t] - v;
        __syncthreads();
        if (t == 255) carry += s[255];
        __syncthreads();
    }
    if (t == 0) binBase[nbins] = carry;
}

// ---- phase 3: scatter packed (src<<shift)|local to deterministic slots ----
__global__ __launch_bounds__(256) void part_scatter2_kernel(
    const int* __restrict__ srcC, const int* __restrict__ dstC,
    const int* __restrict__ srcV, const int* __restrict__ dstV, int E, int nblocks,
    int nbinsC, const int* __restrict__ countsC, const int* __restrict__ binBaseC,
    int* __restrict__ ebufC,
    int nbinsV, const int* __restrict__ countsV, const int* __restrict__ binBaseV,
    int* __restrict__ ebufV) {
    const int *src, *dst, *counts, *binBase; int* ebuf; int shift, mask, nbins; int b;
    if (blockIdx.x < (unsigned)nblocks) {
        src = srcC; dst = dstC; counts = countsC; binBase = binBaseC; ebuf = ebufC;
        shift = 6; mask = 63; nbins = nbinsC; b = blockIdx.x;
    } else {
        src = srcV; dst = dstV; counts = countsV; binBase = binBaseV; ebuf = ebufV;
        shift = 7; mask = 127; nbins = nbinsV; b = blockIdx.x - nblocks;
    }
    __shared__ int hist[MAXBINS];
    int t = threadIdx.x;
    for (int j = t; j < nbins; j += 256) hist[j] = 0;
    __syncthreads();
    int base = b * CHUNK;
#pragma unroll
    for (int j = 0; j < EPT; ++j) {
        int e = base + j * 256 + t;
        if (e < E) {
            int d = dst[e];
            int bin = d >> shift;
            int rank = atomicAdd(&hist[bin], 1);
            int slot = binBase[bin] + counts[(size_t)bin * nblocks + b] + rank;
            ebuf[slot] = (src[e] << shift) | (d & mask);
        }
    }
}

// ---- bucketed mean, 64-dim rows, 64 nodes/bucket ----
__global__ __launch_bounds__(256) void acc64_kernel(
    const int* __restrict__ binBase, const int* __restrict__ ebuf,
    const float* __restrict__ X, float* __restrict__ M, int n) {
    __shared__ float acc[64 * 64];
    __shared__ int cnt[64];
    int t = threadIdx.x, bin = blockIdx.x;
    for (int j = t; j < 64 * 64; j += 256) acc[j] = 0.f;
    if (t < 64) cnt[t] = 0;
    __syncthreads();
    int e0 = binBase[bin], e1 = binBase[bin + 1];
    int lane = t & 63, w = t >> 6;
    for (int eb = e0 + w * 4; eb < e1; eb += 16) {
        int v[4]; float r[4];
#pragma unroll
        for (int j = 0; j < 4; ++j) {
            int e = eb + j;
            v[j] = (e < e1) ? ebuf[e] : -1;
        }
#pragma unroll
        for (int j = 0; j < 4; ++j)
            r[j] = (v[j] >= 0) ? X[(size_t)(v[j] >> 6) * 64 + lane] : 0.f;
#pragma unroll
        for (int j = 0; j < 4; ++j) {
            if (v[j] >= 0) {
                atomicAdd(&acc[(v[j] & 63) * 64 + lane], r[j]);
                if (lane == 0) atomicAdd(&cnt[v[j] & 63], 1);
            }
        }
    }
    __syncthreads();
    int node0 = bin << 6;
    for (int j = t; j < 64 * 64; j += 256) {
        int local = j >> 6, d = j & 63;
        int node = node0 + local;
        if (node < n)
            M[(size_t)node * 64 + d] = acc[j] / fmaxf((float)cnt[local], 1.f);
    }
}

// ---- bucketed mean, 16-dim rows, 128 nodes/bucket ----
__global__ __launch_bounds__(256) void acc16_kernel(
    const int* __restrict__ binBase, const int* __restrict__ ebuf,
    const float* __restrict__ X, float* __restrict__ M, int n) {
    __shared__ float acc[128 * 16];
    __shared__ int cnt[128];
    int t = threadIdx.x, bin = blockIdx.x;
    for (int j = t; j < 128 * 16; j += 256) acc[j] = 0.f;
    if (t < 128) cnt[t] = 0;
    __syncthreads();
    int e0 = binBase[bin], e1 = binBase[bin + 1];
    int lane = t & 63, w = t >> 6;
    int g = lane >> 4, dl = lane & 15;
    for (int eb = e0 + w * 16; eb < e1; eb += 64) {
#pragma unroll
        for (int ss = 0; ss < 4; ++ss) {
            int e = eb + ss * 4 + g;
            int v = (e < e1) ? ebuf[e] : -1;
            float r = (v >= 0) ? X[(size_t)(v >> 7) * 16 + dl] : 0.f;
            if (v >= 0) {
                atomicAdd(&acc[(v & 127) * 16 + dl], r);
                if (dl == 0) atomicAdd(&cnt[v & 127], 1);
            }
        }
    }
    __syncthreads();
    int node0 = bin << 7;
    for (int j = t; j < 128 * 16; j += 256) {
        int local = j >> 4, d = j & 15;
        int node = node0 + local;
        if (node < n)
            M[(size_t)node * 16 + d] = acc[j] / fmaxf((float)cnt[local], 1.f);
    }
}

// ---------------- tile GEMMs (unchanged from round 3) ----------------
template<int D, int ROW0>
__device__ inline void stageF(const float* __restrict__ A, float* __restrict__ Fb,
                              int i0, int n, int t) {
    const int Q = D / 4;
    const int NPP = 256 / Q;
#pragma unroll
    for (int p = 0; p < 64 / NPP; ++p) {
        int nn = t / Q + p * NPP;
        int k4 = t % Q;
        int node = i0 + nn;
        float4 v = make_float4(0.f, 0.f, 0.f, 0.f);
        if (node < n) v = ((const float4*)A)[(size_t)node * Q + k4];
        Fb[(ROW0 + 4 * k4 + 0) * 68 + nn] = v.x;
        Fb[(ROW0 + 4 * k4 + 1) * 68 + nn] = v.y;
        Fb[(ROW0 + 4 * k4 + 2) * 68 + nn] = v.z;
        Fb[(ROW0 + 4 * k4 + 3) * 68 + nn] = v.w;
    }
}

template<int D1, int D2>
__global__ __launch_bounds__(256) void gemm80_relu_kernel(
    const float* __restrict__ M, const float* __restrict__ X,
    const float* __restrict__ Wl, const float* __restrict__ Wr,
    const float* __restrict__ bias, float* __restrict__ H, int n) {
    __shared__ float Fb[80 * 68];
    __shared__ float Wb[80 * 128];
    int t = threadIdx.x;
    int i0 = blockIdx.x * 64;
    {
        const float4* wl4 = (const float4*)Wl;
        const float4* wr4 = (const float4*)Wr;
        float4* wb4 = (float4*)Wb;
        for (int j = t; j < D1 * 32; j += 256) wb4[j] = wl4[j];
        for (int j = t; j < D2 * 32; j += 256) wb4[D1 * 32 + j] = wr4[j];
    }
    stageF<D1, 0>(M, Fb, i0, n, t);
    stageF<D2, D1>(X, Fb, i0, n, t);
    __syncthreads();
    int tc = t & 15, tn = t >> 4;
    int c0 = tc * 4, n0 = tn * 4;
    float acc[4][8];
#pragma unroll
    for (int j = 0; j < 4; ++j)
#pragma unroll
        for (int jj = 0; jj < 8; ++jj) acc[j][jj] = 0.f;
#pragma unroll 4
    for (int k = 0; k < 80; ++k) {
        float4 f  = *(const float4*)&Fb[k * 68 + n0];
        float4 wa = *(const float4*)&Wb[k * 128 + c0];
        float4 wc = *(const float4*)&Wb[k * 128 + 64 + c0];
        float ff[4] = {f.x, f.y, f.z, f.w};
        float va[4] = {wa.x, wa.y, wa.z, wa.w};
        float vb[4] = {wc.x, wc.y, wc.z, wc.w};
#pragma unroll
        for (int j = 0; j < 4; ++j)
#pragma unroll
            for (int jj = 0; jj < 4; ++jj) {
                acc[j][jj]     += ff[j] * va[jj];
                acc[j][4 + jj] += ff[j] * vb[jj];
            }
    }
    float4 blo = ((const float4*)bias)[tc];
    float4 bhi = ((const float4*)bias)[16 + tc];
#pragma unroll
    for (int j = 0; j < 4; ++j) {
        int node = i0 + n0 + j;
        if (node < n) {
            float4 o1, o2;
            o1.x = fmaxf(acc[j][0] + blo.x, 0.f);
            o1.y = fmaxf(acc[j][1] + blo.y, 0.f);
            o1.z = fmaxf(acc[j][2] + blo.z, 0.f);
            o1.w = fmaxf(acc[j][3] + blo.w, 0.f);
            o2.x = fmaxf(acc[j][4] + bhi.x, 0.f);
            o2.y = fmaxf(acc[j][5] + bhi.y, 0.f);
            o2.z = fmaxf(acc[j][6] + bhi.z, 0.f);
            o2.w = fmaxf(acc[j][7] + bhi.w, 0.f);
            ((float4*)H)[(size_t)node * 32 + tc] = o1;
            ((float4*)H)[(size_t)node * 32 + 16 + tc] = o2;
        }
    }
}

__global__ __launch_bounds__(256) void gemm80_w2_kernel(
    const float* __restrict__ M, const float* __restrict__ X,
    const float* __restrict__ Wl, const float* __restrict__ Wr,
    const float* __restrict__ bias, const float* __restrict__ W2,
    float* __restrict__ O, int n) {
    __shared__ float Fb[128 * 68];
    __shared__ float Wb[80 * 128];
    int t = threadIdx.x;
    int i0 = blockIdx.x * 64;
    {
        const float4* wl4 = (const float4*)Wl;
        const float4* wr4 = (const float4*)Wr;
        float4* wb4 = (float4*)Wb;
        for (int j = t; j < 16 * 32; j += 256) wb4[j] = wl4[j];
        for (int j = t; j < 64 * 32; j += 256) wb4[16 * 32 + j] = wr4[j];
    }
    stageF<16, 0>(M, Fb, i0, n, t);
    stageF<64, 16>(X, Fb, i0, n, t);
    __syncthreads();
    int tc = t & 15, tn = t >> 4;
    int c0 = tc * 4, n0 = tn * 4;
    float acc[4][8];
#pragma unroll
    for (int j = 0; j < 4; ++j)
#pragma unroll
        for (int jj = 0; jj < 8; ++jj) acc[j][jj] = 0.f;
#pragma unroll 4
    for (int k = 0; k < 80; ++k) {
        float4 f  = *(const float4*)&Fb[k * 68 + n0];
        float4 wa = *(const float4*)&Wb[k * 128 + c0];
        float4 wc = *(const float4*)&Wb[k * 128 + 64 + c0];
        float ff[4] = {f.x, f.y, f.z, f.w};
        float va[4] = {wa.x, wa.y, wa.z, wa.w};
        float vb[4] = {wc.x, wc.y, wc.z, wc.w};
#pragma unroll
        for (int j = 0; j < 4; ++j)
#pragma unroll
            for (int jj = 0; jj < 4; ++jj) {
                acc[j][jj]     += ff[j] * va[jj];
                acc[j][4 + jj] += ff[j] * vb[jj];
            }
    }
    __syncthreads();
    {
        float4 blo = ((const float4*)bias)[tc];
        float4 bhi = ((const float4*)bias)[16 + tc];
        float bl[8] = {blo.x, blo.y, blo.z, blo.w, bhi.x, bhi.y, bhi.z, bhi.w};
#pragma unroll
        for (int j = 0; j < 4; ++j)
#pragma unroll
            for (int jj = 0; jj < 4; ++jj) {
                Fb[(c0 + jj) * 68 + n0 + j]      = fmaxf(acc[j][jj] + bl[jj], 0.f);
                Fb[(64 + c0 + jj) * 68 + n0 + j] = fmaxf(acc[j][4 + jj] + bl[4 + jj], 0.f);
            }
        const float4* w24 = (const float4*)W2;
        float4* wb4 = (float4*)Wb;
        for (int j = t; j < 128 * 16; j += 256) wb4[j] = w24[j];
    }
    __syncthreads();
    float a2[4][4];
#pragma unroll
    for (int j = 0; j < 4; ++j)
#pragma unroll
        for (int jj = 0; jj < 4; ++jj) a2[j][jj] = 0.f;
#pragma unroll 4
    for (int k = 0; k < 128; ++k) {
        float4 h = *(const float4*)&Fb[k * 68 + n0];
        float4 w = *(const float4*)&Wb[k * 64 + c0];
        float hh[4] = {h.x, h.y, h.z, h.w};
        float ww[4] = {w.x, w.y, w.z, w.w};
#pragma unroll
        for (int j = 0; j < 4; ++j)
#pragma unroll
            for (int jj = 0; jj < 4; ++jj) a2[j][jj] += hh[j] * ww[jj];
    }
#pragma unroll
    for (int j = 0; j < 4; ++j) {
        int node = i0 + n0 + j;
        if (node < n) {
            float4 o = {a2[j][0], a2[j][1], a2[j][2], a2[j][3]};
            ((float4*)O)[(size_t)node * 16 + tc] = o;
        }
    }
}

__global__ __launch_bounds__(256) void gemm128_add_kernel(
    const float* __restrict__ HC, const float* __restrict__ W,
    const float* __restrict__ Madd, const float* __restrict__ bias,
    float* __restrict__ O, int n) {
    __shared__ float Fb[128 * 68];
    __shared__ float Wb[128 * 64];
    int t = threadIdx.x;
    int i0 = blockIdx.x * 64;
    {
        const float4* w4 = (const float4*)W;
        float4* wb4 = (float4*)Wb;
        for (int j = t; j < 128 * 16; j += 256) wb4[j] = w4[j];
    }
    stageF<128, 0>(HC, Fb, i0, n, t);
    __syncthreads();
    int tc = t & 15, tn = t >> 4;
    int c0 = tc * 4, n0 = tn * 4;
    float acc[4][4];
#pragma unroll
    for (int j = 0; j < 4; ++j)
#pragma unroll
        for (int jj = 0; jj < 4; ++jj) acc[j][jj] = 0.f;
#pragma unroll 4
    for (int k = 0; k < 128; ++k) {
        float4 f = *(const float4*)&Fb[k * 68 + n0];
        float4 w = *(const float4*)&Wb[k * 64 + c0];
        float ff[4] = {f.x, f.y, f.z, f.w};
        float ww[4] = {w.x, w.y, w.z, w.w};
#pragma unroll
        for (int j = 0; j < 4; ++j)
#pragma unroll
            for (int jj = 0; jj < 4; ++jj) acc[j][jj] += ff[j] * ww[jj];
    }
    float4 b = ((const float4*)bias)[tc];
#pragma unroll
    for (int j = 0; j < 4; ++j) {
        int node = i0 + n0 + j;
        if (node < n) {
            float4 m = ((const float4*)Madd)[(size_t)node * 16 + tc];
            float4 o;
            o.x = acc[j][0] + m.x + b.x;
            o.y = acc[j][1] + m.y + b.y;
            o.z = acc[j][2] + m.z + b.z;
            o.w = acc[j][3] + m.w + b.w;
            ((float4*)O)[(size_t)node * 16 + tc] = o;
        }
    }
}

extern "C" void kernel_launch(void* const* d_in, const int* in_sizes, int n_in,
                              void* d_out, int out_size, void* d_ws, size_t ws_size,
                              hipStream_t stream) {
    const float* x_var    = (const float*)d_in[0];
    const float* x_config = (const float*)d_in[1];
    const int* src_v2c = (const int*)d_in[2];
    const int* dst_v2c = (const int*)d_in[3];
    const int* src_c2v = (const int*)d_in[4];
    const int* dst_c2v = (const int*)d_in[5];
    const float* Wl1_v2c = (const float*)d_in[7];
    const float* bl1_v2c = (const float*)d_in[8];
    const float* Wr1_v2c = (const float*)d_in[9];
    const float* Wl1_c2v = (const float*)d_in[10];
    const float* bl1_c2v = (const float*)d_in[11];
    const float* Wr1_c2v = (const float*)d_in[12];
    const float* Wl2 = (const float*)d_in[13];
    const float* bl2 = (const float*)d_in[14];
    const float* Wr2 = (const float*)d_in[15];
    float* out = (float*)d_out;

    int NV = in_sizes[0] / 64;
    int NC = in_sizes[1] / 16;
    int E  = in_sizes[2];

    int nblocks = (E + CHUNK - 1) / CHUNK;          // 196
    int nbins_c = (NC + 63) >> 6;                   // 782 (64 nodes/bin)
    int nbins_v = (NV + 127) >> 7;                  // 782 (128 nodes/bin)

    char* p = (char*)d_ws;
    float* Mc  = (float*)p; p += (size_t)NC * 64 * 4;   // reused as Mc2
    float* Mv  = (float*)p; p += (size_t)NV * 16 * 4;
    float* HC  = (float*)p; p += (size_t)NC * 128 * 4;
    float* hv2 = (float*)p; p += (size_t)NV * 64 * 4;
    int* countsC = (int*)p; p += (size_t)nbins_c * nblocks * 4;
    int* countsV = (int*)p; p += (size_t)nbins_v * nblocks * 4;
    int* binTotC = (int*)p; p += (size_t)nbins_c * 4;
    int* binTotV = (int*)p; p += (size_t)nbins_v * 4;
    int* binBaseC = (int*)p; p += (size_t)(nbins_c + 1) * 4;
    int* binBaseV = (int*)p; p += (size_t)(nbins_v + 1) * 4;
    int* ebufC = (int*)p; p += (size_t)E * 4;
    int* ebufV = (int*)p; p += (size_t)E * 4;

    part_count2_kernel<<<2 * nblocks, 256, 0, stream>>>(
        dst_v2c, dst_c2v, E, nblocks, nbins_c, nbins_v, countsC, countsV);
    part_rowscan2_kernel<<<nbins_c + nbins_v, 256, 0, stream>>>(
        countsC, nbins_c, binTotC, countsV, binTotV, nblocks);
    part_binscan2_kernel<<<2, 256, 0, stream>>>(
        binTotC, nbins_c, binBaseC, binTotV, nbins_v, binBaseV);
    part_scatter2_kernel<<<2 * nblocks, 256, 0, stream>>>(
        src_v2c, dst_v2c, src_c2v, dst_c2v, E, nblocks,
        nbins_c, countsC, binBaseC, ebufC,
        nbins_v, countsV, binBaseV, ebufV);

    acc64_kernel<<<nbins_c, 256, 0, stream>>>(binBaseC, ebufC, x_var, Mc, NC);
    acc16_kernel<<<nbins_v, 256, 0, stream>>>(binBaseV, ebufV, x_config, Mv, NV);

    gemm80_relu_kernel<64, 16><<<(NC + 63) / 64, 256, 0, stream>>>(
        Mc, x_config, Wl1_v2c, Wr1_v2c, bl1_v2c, HC, NC);
    gemm80_w2_kernel<<<(NV + 63) / 64, 256, 0, stream>>>(
        Mv, x_var, Wl1_c2v, Wr1_c2v, bl1_c2v, Wl2, hv2, NV);

    float* Mc2 = Mc;   // dead after gemm80_relu
    acc64_kernel<<<nbins_c, 256, 0, stream>>>(binBaseC, ebufC, hv2, Mc2, NC);

    gemm128_add_kernel<<<(NC + 63) / 64, 256, 0, stream>>>(HC, Wr2, Mc2, bl2, out, NC);
}

// Round 5
// 337.538 us; speedup vs baseline: 3.0630x; 3.0630x over previous
//
#include <hip/hip_runtime.h>

// 2-layer hetero SAGEConv, fully global-atomic-free:
//   radix partition by dst-bucket (LDS histograms) -> per-bucket local CSR
//   (LDS scan/rank) -> wave-per-node gather-mean -> dense tile GEMMs with
//   fused in-tile second-stage (@Wl2 for var path, @Wr2+bl2 for config path).
//  - (msum/cnt)@W == (msum@W)/cnt
//  - h_var and h_config are never materialized in global memory.
//  - to_dense_batch is an identity reshape (batch = arange(NC)//K).

#define CHUNK 4096      // edges per partition block
#define EPT 16          // edges per thread (CHUNK/256)
#define MAXBINS 1024

// ---- partition phase 1: counts[bin][block], no global atomics ----
__global__ __launch_bounds__(256) void part_count2_kernel(
    const int* __restrict__ dstC, const int* __restrict__ dstV, int E, int nblocks,
    int nbinsC, int nbinsV, int* __restrict__ countsC, int* __restrict__ countsV) {
    const int* dst; int shift, nbins; int* counts; int b;
    if (blockIdx.x < (unsigned)nblocks) { dst = dstC; shift = 6; nbins = nbinsC; counts = countsC; b = blockIdx.x; }
    else { dst = dstV; shift = 7; nbins = nbinsV; counts = countsV; b = blockIdx.x - nblocks; }
    __shared__ int hist[MAXBINS];
    int t = threadIdx.x;
    for (int j = t; j < nbins; j += 256) hist[j] = 0;
    __syncthreads();
    int base = b * CHUNK;
#pragma unroll
    for (int j = 0; j < EPT; ++j) {
        int e = base + j * 256 + t;
        if (e < E) atomicAdd(&hist[dst[e] >> shift], 1);
    }
    __syncthreads();
    for (int j = t; j < nbins; j += 256) counts[(size_t)j * nblocks + b] = hist[j];
}

// ---- phase 2a: per-bin exclusive prefix over blocks; binTot ----
__global__ __launch_bounds__(256) void part_rowscan2_kernel(
    int* __restrict__ countsC, int nbinsC, int* __restrict__ binTotC,
    int* __restrict__ countsV, int* __restrict__ binTotV, int nblocks) {
    int* counts; int* binTot; int bin;
    if (blockIdx.x < (unsigned)nbinsC) { counts = countsC; binTot = binTotC; bin = blockIdx.x; }
    else { counts = countsV; binTot = binTotV; bin = blockIdx.x - nbinsC; }
    __shared__ int s[256];
    int t = threadIdx.x;
    int v = (t < nblocks) ? counts[(size_t)bin * nblocks + t] : 0;
    s[t] = v; __syncthreads();
    for (int o = 1; o < 256; o <<= 1) {
        int add = (t >= o) ? s[t - o] : 0; __syncthreads();
        s[t] += add; __syncthreads();
    }
    if (t < nblocks) counts[(size_t)bin * nblocks + t] = s[t] - v;
    if (t == nblocks - 1) binTot[bin] = s[t];
}

// ---- phase 2b: exclusive prefix over bins ----
__global__ __launch_bounds__(256) void part_binscan2_kernel(
    const int* __restrict__ binTotC, int nbinsC, int* __restrict__ binBaseC,
    const int* __restrict__ binTotV, int nbinsV, int* __restrict__ binBaseV) {
    const int* binTot; int nbins; int* binBase;
    if (blockIdx.x == 0) { binTot = binTotC; nbins = nbinsC; binBase = binBaseC; }
    else { binTot = binTotV; nbins = nbinsV; binBase = binBaseV; }
    __shared__ int s[256];
    __shared__ int carry;
    int t = threadIdx.x;
    if (t == 0) carry = 0;
    __syncthreads();
    for (int c0 = 0; c0 < nbins; c0 += 256) {
        int v = (c0 + t < nbins) ? binTot[c0 + t] : 0;
        s[t] = v; __syncthreads();
        for (int o = 1; o < 256; o <<= 1) {
            int add = (t >= o) ? s[t - o] : 0; __syncthreads();
            s[t] += add; __syncthreads();
        }
        if (c0 + t < nbins) binBase[c0 + t] = carry + s[t] - v;
        __syncthreads();
        if (t == 255) carry += s[255];
        __syncthreads();
    }
    if (t == 0) binBase[nbins] = carry;
}

// ---- phase 3: scatter packed (src<<shift)|local to deterministic slots ----
__global__ __launch_bounds__(256) void part_scatter2_kernel(
    const int* __restrict__ srcC, const int* __restrict__ dstC,
    const int* __restrict__ srcV, const int* __restrict__ dstV, int E, int nblocks,
    int nbinsC, const int* __restrict__ countsC, const int* __restrict__ binBaseC,
    int* __restrict__ ebufC,
    int nbinsV, const int* __restrict__ countsV, const int* __restrict__ binBaseV,
    int* __restrict__ ebufV) {
    const int *src, *dst, *counts, *binBase; int* ebuf; int shift, mask, nbins; int b;
    if (blockIdx.x < (unsigned)nblocks) {
        src = srcC; dst = dstC; counts = countsC; binBase = binBaseC; ebuf = ebufC;
        shift = 6; mask = 63; nbins = nbinsC; b = blockIdx.x;
    } else {
        src = srcV; dst = dstV; counts = countsV; binBase = binBaseV; ebuf = ebufV;
        shift = 7; mask = 127; nbins = nbinsV; b = blockIdx.x - nblocks;
    }
    __shared__ int hist[MAXBINS];
    int t = threadIdx.x;
    for (int j = t; j < nbins; j += 256) hist[j] = 0;
    __syncthreads();
    int base = b * CHUNK;
#pragma unroll
    for (int j = 0; j < EPT; ++j) {
        int e = base + j * 256 + t;
        if (e < E) {
            int d = dst[e];
            int bin = d >> shift;
            int rank = atomicAdd(&hist[bin], 1);
            int slot = binBase[bin] + counts[(size_t)bin * nblocks + b] + rank;
            ebuf[slot] = (src[e] << shift) | (d & mask);
        }
    }
}

// ---- phase 4: per-bucket local CSR (LDS only): ebuf2 per-node-ordered + off ----
__global__ __launch_bounds__(256) void csr2_kernel(
    int nbinsC, const int* __restrict__ binBaseC, const int* __restrict__ ebufC,
    int* __restrict__ ebufC2, int* __restrict__ offC, int nC,
    const int* __restrict__ binBaseV, const int* __restrict__ ebufV,
    int* __restrict__ ebufV2, int* __restrict__ offV, int nV, int E) {
    __shared__ int hist[128];
    __shared__ int cur[128];
    __shared__ int s[256];
    int t = threadIdx.x;
    const int *binBase, *eb1; int *eb2, *off; int n, shift, bin;
    if (blockIdx.x < (unsigned)nbinsC) {
        bin = blockIdx.x; binBase = binBaseC; eb1 = ebufC; eb2 = ebufC2; off = offC; n = nC; shift = 6;
    } else {
        bin = blockIdx.x - nbinsC; binBase = binBaseV; eb1 = ebufV; eb2 = ebufV2; off = offV; n = nV; shift = 7;
    }
    int mask = (1 << shift) - 1, nloc = 1 << shift;
    if (blockIdx.x == 0 && t == 0) { offC[nC] = E; offV[nV] = E; }
    int e0 = binBase[bin], e1 = binBase[bin + 1];
    if (t < nloc) { hist[t] = 0; cur[t] = 0; }
    __syncthreads();
    for (int e = e0 + t; e < e1; e += 256) atomicAdd(&hist[eb1[e] & mask], 1);
    __syncthreads();
    int v = (t < nloc) ? hist[t] : 0;
    s[t] = v; __syncthreads();
    for (int o = 1; o < 256; o <<= 1) {
        int add = (t >= o) ? s[t - o] : 0; __syncthreads();
        s[t] += add; __syncthreads();
    }
    if (t < nloc) {
        int node = (bin << shift) + t;
        if (node < n) off[node] = e0 + s[t] - v;
        hist[t] = s[t] - v;   // reuse as local exclusive offset
    }
    __syncthreads();
    for (int e = e0 + t; e < e1; e += 256) {
        int w = eb1[e];
        int local = w & mask;
        int r = atomicAdd(&cur[local], 1);
        eb2[e0 + hist[local] + r] = w >> shift;
    }
}

// ---- wave-per-node gather-mean bodies ----
__device__ __forceinline__ void gather64_body(
    const int* __restrict__ off, const int* __restrict__ eb,
    const float* __restrict__ X, float* __restrict__ M,
    const float* __restrict__ P, float* __restrict__ out,
    int n, int b, int nblocks) {
    int lane = threadIdx.x & 63, wid = threadIdx.x >> 6;
    int nw = nblocks * 4;
    for (int i = b * 4 + wid; i < n; i += nw) {
        int e0 = off[i], e1 = off[i + 1];
        int deg = e1 - e0;
        float acc = 0.f;
        for (int j0 = 0; j0 < deg; j0 += 64) {
            int m = min(deg - j0, 64);
            int idx = 0;
            if (lane < m) idx = eb[e0 + j0 + lane];
            int j = 0;
            for (; j + 4 <= m; j += 4) {
                int s0 = __shfl(idx, j);
                int s1 = __shfl(idx, j + 1);
                int s2 = __shfl(idx, j + 2);
                int s3 = __shfl(idx, j + 3);
                acc += X[(size_t)s0 * 64 + lane];
                acc += X[(size_t)s1 * 64 + lane];
                acc += X[(size_t)s2 * 64 + lane];
                acc += X[(size_t)s3 * 64 + lane];
            }
            for (; j < m; ++j) {
                int s = __shfl(idx, j);
                acc += X[(size_t)s * 64 + lane];
            }
        }
        float r = acc / fmaxf((float)deg, 1.0f);
        if (out) out[(size_t)i * 64 + lane] = r + P[(size_t)i * 64 + lane];
        else     M[(size_t)i * 64 + lane] = r;
    }
}

__device__ __forceinline__ void gather16_body(
    const int* __restrict__ off, const int* __restrict__ eb,
    const float* __restrict__ X, float* __restrict__ M, int n, int b, int nblocks) {
    int lane = threadIdx.x & 63, wid = threadIdx.x >> 6;
    int dlane = lane & 15, eg = lane >> 4;
    int nw = nblocks * 4;
    for (int i = b * 4 + wid; i < n; i += nw) {
        int e0 = off[i], e1 = off[i + 1];
        int deg = e1 - e0;
        float acc = 0.f;
        for (int j0 = 0; j0 < deg; j0 += 64) {
            int m = min(deg - j0, 64);
            int idx = 0;
            if (lane < m) idx = eb[e0 + j0 + lane];
            for (int j = eg; j < m; j += 4) {
                int s = __shfl(idx, j);
                acc += X[(size_t)s * 16 + dlane];
            }
        }
        acc += __shfl_xor(acc, 16);
        acc += __shfl_xor(acc, 32);
        if (lane < 16) M[(size_t)i * 16 + lane] = acc / fmaxf((float)deg, 1.0f);
    }
}

// combined layer-1 gathers (independent)
__global__ __launch_bounds__(256) void gather2_kernel(
    const int* __restrict__ offC, const int* __restrict__ ebC,
    const float* __restrict__ Xc, float* __restrict__ Mc, int nC, int gbC,
    const int* __restrict__ offV, const int* __restrict__ ebV,
    const float* __restrict__ Xv, float* __restrict__ Mv, int nV, int gbV) {
    if (blockIdx.x < (unsigned)gbC)
        gather64_body(offC, ebC, Xc, Mc, nullptr, nullptr, nC, blockIdx.x, gbC);
    else
        gather16_body(offV, ebV, Xv, Mv, nV, blockIdx.x - gbC, gbV);
}

// layer-2 gather fused with final add: out = mean(hv2) + OCp
__global__ __launch_bounds__(256) void gather64_add_kernel(
    const int* __restrict__ off, const int* __restrict__ eb,
    const float* __restrict__ X, const float* __restrict__ P,
    float* __restrict__ out, int n) {
    gather64_body(off, eb, X, nullptr, P, out, n, blockIdx.x, gridDim.x);
}

// ---------------- fused tile GEMM ----------------
// stage1: H[64nodes][128] = relu(M[:,D1] @ Wl + X[:,D2] @ Wr + bias)   (in LDS)
// stage2: O[64nodes][64]  = H @ W2 (+ bias2 if HASB2)
template<int D, int ROW0>
__device__ __forceinline__ void stageF(const float* __restrict__ A, float* __restrict__ Fb,
                                       int i0, int n, int t) {
    const int Q = D / 4;
    const int NPP = 256 / Q;
#pragma unroll
    for (int p = 0; p < 64 / NPP; ++p) {
        int nn = t / Q + p * NPP;
        int k4 = t % Q;
        int node = i0 + nn;
        float4 v = make_float4(0.f, 0.f, 0.f, 0.f);
        if (node < n) v = ((const float4*)A)[(size_t)node * Q + k4];
        Fb[(ROW0 + 4 * k4 + 0) * 68 + nn] = v.x;
        Fb[(ROW0 + 4 * k4 + 1) * 68 + nn] = v.y;
        Fb[(ROW0 + 4 * k4 + 2) * 68 + nn] = v.z;
        Fb[(ROW0 + 4 * k4 + 3) * 68 + nn] = v.w;
    }
}

template<int D1, int D2, bool HASB2>
__global__ __launch_bounds__(256) void gemm80_fused_kernel(
    const float* __restrict__ M, const float* __restrict__ X,
    const float* __restrict__ Wl, const float* __restrict__ Wr,
    const float* __restrict__ bias, const float* __restrict__ W2,
    const float* __restrict__ bias2, float* __restrict__ O, int n) {
    __shared__ float Fb[128 * 68];
    __shared__ float Wb[80 * 128];
    int t = threadIdx.x;
    int i0 = blockIdx.x * 64;
    {
        const float4* wl4 = (const float4*)Wl;
        const float4* wr4 = (const float4*)Wr;
        float4* wb4 = (float4*)Wb;
        for (int j = t; j < D1 * 32; j += 256) wb4[j] = wl4[j];
        for (int j = t; j < D2 * 32; j += 256) wb4[D1 * 32 + j] = wr4[j];
    }
    stageF<D1, 0>(M, Fb, i0, n, t);
    stageF<D2, D1>(X, Fb, i0, n, t);
    __syncthreads();
    int tc = t & 15, tn = t >> 4;
    int c0 = tc * 4, n0 = tn * 4;
    float acc[4][8];
#pragma unroll
    for (int j = 0; j < 4; ++j)
#pragma unroll
        for (int jj = 0; jj < 8; ++jj) acc[j][jj] = 0.f;
#pragma unroll 4
    for (int k = 0; k < D1 + D2; ++k) {
        float4 f  = *(const float4*)&Fb[k * 68 + n0];
        float4 wa = *(const float4*)&Wb[k * 128 + c0];
        float4 wc = *(const float4*)&Wb[k * 128 + 64 + c0];
        float ff[4] = {f.x, f.y, f.z, f.w};
        float va[4] = {wa.x, wa.y, wa.z, wa.w};
        float vb[4] = {wc.x, wc.y, wc.z, wc.w};
#pragma unroll
        for (int j = 0; j < 4; ++j)
#pragma unroll
            for (int jj = 0; jj < 4; ++jj) {
                acc[j][jj]     += ff[j] * va[jj];
                acc[j][4 + jj] += ff[j] * vb[jj];
            }
    }
    __syncthreads();   // all reads of Fb/Wb stage-1 done
    {
        float4 blo = ((const float4*)bias)[tc];
        float4 bhi = ((const float4*)bias)[16 + tc];
        float bl[8] = {blo.x, blo.y, blo.z, blo.w, bhi.x, bhi.y, bhi.z, bhi.w};
#pragma unroll
        for (int j = 0; j < 4; ++j)
#pragma unroll
            for (int jj = 0; jj < 4; ++jj) {
                Fb[(c0 + jj) * 68 + n0 + j]      = fmaxf(acc[j][jj] + bl[jj], 0.f);
                Fb[(64 + c0 + jj) * 68 + n0 + j] = fmaxf(acc[j][4 + jj] + bl[4 + jj], 0.f);
            }
        const float4* w24 = (const float4*)W2;
        float4* wb4 = (float4*)Wb;
        for (int j = t; j < 128 * 16; j += 256) wb4[j] = w24[j];
    }
    __syncthreads();
    float a2[4][4];
#pragma unroll
    for (int j = 0; j < 4; ++j)
#pragma unroll
        for (int jj = 0; jj < 4; ++jj) a2[j][jj] = 0.f;
#pragma unroll 4
    for (int k = 0; k < 128; ++k) {
        float4 h = *(const float4*)&Fb[k * 68 + n0];
        float4 w = *(const float4*)&Wb[k * 64 + c0];
        float hh[4] = {h.x, h.y, h.z, h.w};
        float ww[4] = {w.x, w.y, w.z, w.w};
#pragma unroll
        for (int j = 0; j < 4; ++j)
#pragma unroll
            for (int jj = 0; jj < 4; ++jj) a2[j][jj] += hh[j] * ww[jj];
    }
    float4 b2 = HASB2 ? ((const float4*)bias2)[tc] : make_float4(0.f, 0.f, 0.f, 0.f);
#pragma unroll
    for (int j = 0; j < 4; ++j) {
        int node = i0 + n0 + j;
        if (node < n) {
            float4 o = {a2[j][0] + b2.x, a2[j][1] + b2.y, a2[j][2] + b2.z, a2[j][3] + b2.w};
            ((float4*)O)[(size_t)node * 16 + tc] = o;
        }
    }
}

extern "C" void kernel_launch(void* const* d_in, const int* in_sizes, int n_in,
                              void* d_out, int out_size, void* d_ws, size_t ws_size,
                              hipStream_t stream) {
    const float* x_var    = (const float*)d_in[0];
    const float* x_config = (const float*)d_in[1];
    const int* src_v2c = (const int*)d_in[2];
    const int* dst_v2c = (const int*)d_in[3];
    const int* src_c2v = (const int*)d_in[4];
    const int* dst_c2v = (const int*)d_in[5];
    const float* Wl1_v2c = (const float*)d_in[7];
    const float* bl1_v2c = (const float*)d_in[8];
    const float* Wr1_v2c = (const float*)d_in[9];
    const float* Wl1_c2v = (const float*)d_in[10];
    const float* bl1_c2v = (const float*)d_in[11];
    const float* Wr1_c2v = (const float*)d_in[12];
    const float* Wl2 = (const float*)d_in[13];
    const float* bl2 = (const float*)d_in[14];
    const float* Wr2 = (const float*)d_in[15];
    float* out = (float*)d_out;

    int NV = in_sizes[0] / 64;
    int NC = in_sizes[1] / 16;
    int E  = in_sizes[2];

    int nblocks = (E + CHUNK - 1) / CHUNK;          // 196 (<=256 for rowscan)
    int nbins_c = (NC + 63) >> 6;                   // 64 config nodes / bucket
    int nbins_v = (NV + 127) >> 7;                  // 128 var nodes / bucket

    char* p = (char*)d_ws;
    float* Mc  = (float*)p; p += (size_t)NC * 64 * 4;
    float* Mv  = (float*)p; p += (size_t)NV * 16 * 4;
    float* OCp = (float*)p; p += (size_t)NC * 64 * 4;   // h_config@Wr2 + bl2
    float* hv2 = (float*)p; p += (size_t)NV * 64 * 4;   // h_var@Wl2
    int* countsC = (int*)p; p += (size_t)nbins_c * nblocks * 4;
    int* countsV = (int*)p; p += (size_t)nbins_v * nblocks * 4;
    int* binTotC = (int*)p; p += (size_t)nbins_c * 4;
    int* binTotV = (int*)p; p += (size_t)nbins_v * 4;
    int* binBaseC = (int*)p; p += (size_t)(nbins_c + 1) * 4;
    int* binBaseV = (int*)p; p += (size_t)(nbins_v + 1) * 4;
    int* offC = (int*)p; p += (size_t)(NC + 1) * 4;
    int* offV = (int*)p; p += (size_t)(NV + 1) * 4;
    int* ebufC  = (int*)p; p += (size_t)E * 4;
    int* ebufV  = (int*)p; p += (size_t)E * 4;
    int* ebufC2 = (int*)p; p += (size_t)E * 4;
    int* ebufV2 = (int*)p; p += (size_t)E * 4;

    part_count2_kernel<<<2 * nblocks, 256, 0, stream>>>(
        dst_v2c, dst_c2v, E, nblocks, nbins_c, nbins_v, countsC, countsV);
    part_rowscan2_kernel<<<nbins_c + nbins_v, 256, 0, stream>>>(
        countsC, nbins_c, binTotC, countsV, binTotV, nblocks);
    part_binscan2_kernel<<<2, 256, 0, stream>>>(
        binTotC, nbins_c, binBaseC, binTotV, nbins_v, binBaseV);
    part_scatter2_kernel<<<2 * nblocks, 256, 0, stream>>>(
        src_v2c, dst_v2c, src_c2v, dst_c2v, E, nblocks,
        nbins_c, countsC, binBaseC, ebufC,
        nbins_v, countsV, binBaseV, ebufV);
    csr2_kernel<<<nbins_c + nbins_v, 256, 0, stream>>>(
        nbins_c, binBaseC, ebufC, ebufC2, offC, NC,
        binBaseV, ebufV, ebufV2, offV, NV, E);

    int gbC = (NC + 3) / 4, gbV = (NV + 3) / 4;
    gather2_kernel<<<gbC + gbV, 256, 0, stream>>>(
        offC, ebufC2, x_var, Mc, NC, gbC,
        offV, ebufV2, x_config, Mv, NV, gbV);

    gemm80_fused_kernel<64, 16, true><<<(NC + 63) / 64, 256, 0, stream>>>(
        Mc, x_config, Wl1_v2c, Wr1_v2c, bl1_v2c, Wr2, bl2, OCp, NC);
    gemm80_fused_kernel<16, 64, false><<<(NV + 63) / 64, 256, 0, stream>>>(
        Mv, x_var, Wl1_c2v, Wr1_c2v, bl1_c2v, Wl2, nullptr, hv2, NV);

    gather64_add_kernel<<<gbC, 256, 0, stream>>>(offC, ebufC2, hv2, OCp, out, NC);
}